// Round 5
// baseline (616.489 us; speedup 1.0000x reference)
//
#include <hip/hip_runtime.h>

// SparseTransE scoring — R4 DIAGNOSTIC build (resubmit after broker timeout;
// expected ~660-700us, not a perf attempt).
//
// Purpose: the real score kernel (~285us) sits just below the rocprof top-5
// cutoff (harness fills ~315us), so we have never seen its counters, and no
// model (traffic ~70us / Little's-law MLP / compute ~20us) explains 285us.
// This build runs the score pipeline TWICE per wave:
//   rep0: cold pass, identical to the proven R1 kernel, stores real results.
//   rep1: same indices re-computed from a laundered (CSE-proof) emb pointer,
//         result consumed by an empty asm — rows are L2/L3-warm, so rep1
//         isolates the on-chip + compute cost; rep0-rep1 split = HBM-path cost.
// sched_barrier(0) stops the scheduler hoisting rep1 loads into rep0 (which
// would double MLP and muddy the cold/warm separation).
//
// Read as: dur = 285 + warm_pass. FETCH_SIZE confirms (or refutes) the ~270MB
// demand-traffic model. Correctness identical to R1 (rep1 writes nothing).

#define EMB 256
#define EPS 1e-12f
#define SPW 4

__global__ __launch_bounds__(256) void transe_score_diag2x_kernel(
    const float* __restrict__ emb,
    const int* __restrict__ pos_h, const int* __restrict__ pos_r, const int* __restrict__ pos_t,
    const int* __restrict__ neg_h, const int* __restrict__ neg_r, const int* __restrict__ neg_t,
    const int* __restrict__ n_ent_ptr,
    float* __restrict__ out, int B)
{
    const int wave = (blockIdx.x * blockDim.x + threadIdx.x) >> 6;
    const int lane = threadIdx.x & 63;
    const int base = wave * SPW;
    if (base >= 2 * B) return;

    const int n_ent = *n_ent_ptr;

    const int* __restrict__ hsrc;
    const int* __restrict__ rsrc;
    const int* __restrict__ tsrc;
    int off;
    if (base < B) { hsrc = pos_h; rsrc = pos_r; tsrc = pos_t; off = base; }
    else          { hsrc = neg_h; rsrc = neg_r; tsrc = neg_t; off = base - B; }

    const int4 hh = *(const int4*)(hsrc + off);
    const int4 rr = *(const int4*)(rsrc + off);
    const int4 tt = *(const int4*)(tsrc + off);

    const int hi[SPW] = {hh.x, hh.y, hh.z, hh.w};
    const int ri[SPW] = {rr.x, rr.y, rr.z, rr.w};
    const int ti[SPW] = {tt.x, tt.y, tt.z, tt.w};

    // ---------------- rep0: cold pass (identical to R1) ----------------
    {
        float4 hv[SPW], tv[SPW], rv[SPW];
#pragma unroll
        for (int s = 0; s < SPW; ++s) {
            hv[s] = ((const float4*)(emb + (size_t)hi[s] * EMB))[lane];
            tv[s] = ((const float4*)(emb + (size_t)ti[s] * EMB))[lane];
            rv[s] = ((const float4*)(emb + ((size_t)ri[s] + (size_t)n_ent) * EMB))[lane];
        }

        float red[2 * SPW];
#pragma unroll
        for (int s = 0; s < SPW; ++s) {
            red[s]       = hv[s].x * hv[s].x + hv[s].y * hv[s].y + hv[s].z * hv[s].z + hv[s].w * hv[s].w;
            red[SPW + s] = tv[s].x * tv[s].x + tv[s].y * tv[s].y + tv[s].z * tv[s].z + tv[s].w * tv[s].w;
        }
#pragma unroll
        for (int d = 32; d >= 1; d >>= 1) {
#pragma unroll
            for (int k = 0; k < 2 * SPW; ++k)
                red[k] += __shfl_xor(red[k], d, 64);
        }

        float sq[SPW];
#pragma unroll
        for (int s = 0; s < SPW; ++s) {
            const float inh = 1.0f / fmaxf(sqrtf(red[s]), EPS);
            const float itn = 1.0f / fmaxf(sqrtf(red[SPW + s]), EPS);
            const float vx = hv[s].x * inh + rv[s].x - tv[s].x * itn;
            const float vy = hv[s].y * inh + rv[s].y - tv[s].y * itn;
            const float vz = hv[s].z * inh + rv[s].z - tv[s].z * itn;
            const float vw = hv[s].w * inh + rv[s].w - tv[s].w * itn;
            sq[s] = vx * vx + vy * vy + vz * vz + vw * vw;
        }
#pragma unroll
        for (int d = 32; d >= 1; d >>= 1) {
#pragma unroll
            for (int k = 0; k < SPW; ++k)
                sq[k] += __shfl_xor(sq[k], d, 64);
        }

        if (lane == 0)
            *(float4*)(out + base) = make_float4(-sq[0], -sq[1], -sq[2], -sq[3]);
    }

    // Fence: nothing from rep1 may be hoisted into rep0's window.
    __builtin_amdgcn_sched_barrier(0);

    // ---------------- rep1: warm pass (same indices, laundered base) ----------
    unsigned long long p = (unsigned long long)(const void*)emb;
    asm volatile("" : "+s"(p));           // compiler can no longer CSE vs rep0
    const float* emb2 = (const float*)p;

    {
        float4 hv[SPW], tv[SPW], rv[SPW];
#pragma unroll
        for (int s = 0; s < SPW; ++s) {
            hv[s] = ((const float4*)(emb2 + (size_t)hi[s] * EMB))[lane];
            tv[s] = ((const float4*)(emb2 + (size_t)ti[s] * EMB))[lane];
            rv[s] = ((const float4*)(emb2 + ((size_t)ri[s] + (size_t)n_ent) * EMB))[lane];
        }

        float red[2 * SPW];
#pragma unroll
        for (int s = 0; s < SPW; ++s) {
            red[s]       = hv[s].x * hv[s].x + hv[s].y * hv[s].y + hv[s].z * hv[s].z + hv[s].w * hv[s].w;
            red[SPW + s] = tv[s].x * tv[s].x + tv[s].y * tv[s].y + tv[s].z * tv[s].z + tv[s].w * tv[s].w;
        }
#pragma unroll
        for (int d = 32; d >= 1; d >>= 1) {
#pragma unroll
            for (int k = 0; k < 2 * SPW; ++k)
                red[k] += __shfl_xor(red[k], d, 64);
        }

        float sq[SPW];
#pragma unroll
        for (int s = 0; s < SPW; ++s) {
            const float inh = 1.0f / fmaxf(sqrtf(red[s]), EPS);
            const float itn = 1.0f / fmaxf(sqrtf(red[SPW + s]), EPS);
            const float vx = hv[s].x * inh + rv[s].x - tv[s].x * itn;
            const float vy = hv[s].y * inh + rv[s].y - tv[s].y * itn;
            const float vz = hv[s].z * inh + rv[s].z - tv[s].z * itn;
            const float vw = hv[s].w * inh + rv[s].w - tv[s].w * itn;
            sq[s] = vx * vx + vy * vy + vz * vz + vw * vw;
        }
#pragma unroll
        for (int d = 32; d >= 1; d >>= 1) {
#pragma unroll
            for (int k = 0; k < SPW; ++k)
                sq[k] += __shfl_xor(sq[k], d, 64);
        }

        // Keep rep1 alive without any observable store (values are bit-identical
        // to rep0's anyway, but we never write them).
        asm volatile("" :: "v"(sq[0]), "v"(sq[1]), "v"(sq[2]), "v"(sq[3]));
    }
}

extern "C" void kernel_launch(void* const* d_in, const int* in_sizes, int n_in,
                              void* d_out, int out_size, void* d_ws, size_t ws_size,
                              hipStream_t stream) {
    const float* emb  = (const float*)d_in[0];
    const int* pos_h  = (const int*)d_in[1];
    const int* pos_r  = (const int*)d_in[2];
    const int* pos_t  = (const int*)d_in[3];
    const int* neg_h  = (const int*)d_in[4];
    const int* neg_r  = (const int*)d_in[5];
    const int* neg_t  = (const int*)d_in[6];
    const int* n_ent  = (const int*)d_in[7];
    float* out = (float*)d_out;

    const int B = in_sizes[1];               // 65536
    const int total = 2 * B;                 // 131072 scores
    const int waves = (total + SPW - 1) / SPW;
    const int block = 256;                   // 4 waves/block
    const int grid = (waves * 64 + block - 1) / block;

    transe_score_diag2x_kernel<<<grid, block, 0, stream>>>(
        emb, pos_h, pos_r, pos_t, neg_h, neg_r, neg_t, n_ent, out, B);
}